// Round 9
// baseline (704.677 us; speedup 1.0000x reference)
//
#include <hip/hip_runtime.h>

#define DEV_INLINE __device__ __forceinline__

typedef int i32x4 __attribute__((ext_vector_type(4)));
typedef int i32x16 __attribute__((ext_vector_type(16)));

DEV_INLINE int dot4(int a, int b, int c) {
#if __has_builtin(__builtin_amdgcn_sdot4)
    return __builtin_amdgcn_sdot4(a, b, c, false);
#else
    return c
        + (int)(signed char)(a)       * (int)(signed char)(b)
        + (int)(signed char)(a >> 8)  * (int)(signed char)(b >> 8)
        + (int)(signed char)(a >> 16) * (int)(signed char)(b >> 16)
        + (int)(signed char)(a >> 24) * (int)(signed char)(b >> 24);
#endif
}

typedef __attribute__((address_space(1))) const unsigned int guint;
typedef __attribute__((address_space(3))) unsigned int luint;

DEV_INLINE void async_cp16(const signed char* g, signed char* l) {
    __builtin_amdgcn_global_load_lds((guint*)g, (luint*)l, 16, 0, 0);
}

// ---------------- conversion kernels ----------------

// Repack weights to 32-wide MFMA B-fragment-major order, K tap-major:
//   step = tap*CP + cpair; lane holds B[oc%32][c = cpair*32 + (lane>>5)*16 + j of tap]
__global__ void cvt_w_frag32(const float* __restrict__ w, signed char* __restrict__ o,
                             int O, int I, int KK, int CP, int KSTEPS) {
    int idx = blockIdx.x * blockDim.x + threadIdx.x;
    int total = (O >> 5) * KSTEPS * 1024;
    if (idx >= total) return;
    int j = idx & 15;
    int lane = (idx >> 4) & 63;
    int step = (idx >> 10) % KSTEPS;
    int tile = idx / (KSTEPS << 10);
    int oc = tile * 32 + (lane & 31);
    int tap = step / CP;
    int cpair = step - tap * CP;
    int c = cpair * 32 + ((lane >> 5) << 4) + j;
    float v = w[((size_t)oc * I + c) * KK + tap];
    o[idx] = (signed char)(int)v;
}

// conv1 weights: OIHW [96][3][5][5] fp32 -> [96][128] int8, byte [oc][tap*4+c]
__global__ void cvt_w1(const float* __restrict__ w, signed char* __restrict__ o) {
    int idx = blockIdx.x * blockDim.x + threadIdx.x;
    if (idx >= 96 * 128) return;
    int b = idx & 127;
    int oc = idx >> 7;
    int tap = b >> 2;
    int c = b & 3;
    float v = (tap < 25 && c < 3) ? w[(oc * 3 + c) * 25 + tap] : 0.0f;
    o[idx] = (signed char)(int)v;
}

__global__ void cvt_i8(const float* __restrict__ w, signed char* __restrict__ o, int n) {
    int idx = blockIdx.x * blockDim.x + threadIdx.x;
    if (idx < n) o[idx] = (signed char)(int)w[idx];
}

__global__ void cvt_i32(const float* __restrict__ b, int* __restrict__ o, int n) {
    int idx = blockIdx.x * blockDim.x + threadIdx.x;
    if (idx < n) o[idx] = (int)b[idx];
}

// ---------------- quantize input: NCHW fp32 [512,3,32,32] -> NHWC int8 [512,32,32,4] ----------------

__global__ void quantize_in(const float* __restrict__ x, signed char* __restrict__ q, int total) {
    int idx = blockIdx.x * blockDim.x + threadIdx.x;
    if (idx >= total) return;
    int hw = idx & 1023;
    int n = idx >> 10;
    const float* xp = x + n * 3072 + hw;
    int b[4];
#pragma unroll
    for (int c = 0; c < 3; ++c) {
        float v = rintf(xp[c * 1024] / 0.05f);
        v = fminf(fmaxf(v, -128.0f), 127.0f);
        b[c] = (int)v;
    }
    b[3] = 0;
    int packed = (b[0] & 0xff) | ((b[1] & 0xff) << 8) | ((b[2] & 0xff) << 16) | (b[3] << 24);
    ((int*)q)[idx] = packed;
}

// ---------------- conv1 MFMA with LDS im2col (16x16x64, Cin=4) ----------------

__global__ void conv1_mfma(const signed char* __restrict__ act,
                           const signed char* __restrict__ wq,
                           const int* __restrict__ bias,
                           signed char* __restrict__ out) {
    __shared__ int lds[64 * 36];

    int tid = threadIdx.x;
    int lane = tid & 63;
    int wid = tid >> 6;
    int siteBase = blockIdx.x * 64;

    {
        int site_local = tid >> 2;
        int g = tid & 3;
        int site = siteBase + site_local;
        int ox = site & 31;
        int oy = (site >> 5) & 31;
        int n = site >> 10;
        const int* aI = (const int*)act;
        int* dst = lds + site_local * 36 + g * 8;
#pragma unroll
        for (int j = 0; j < 8; ++j) {
            int tap = g * 8 + j;
            int v = 0;
            if (tap < 25) {
                int ky = tap / 5;
                int kx = tap - ky * 5;
                int iy = oy - 2 + ky;
                int ix = ox - 2 + kx;
                if ((unsigned)iy < 32u && (unsigned)ix < 32u)
                    v = aI[(n << 10) + (iy << 5) + ix];
            }
            dst[j] = v;
        }
    }

    int m = lane & 15;
    int q = lane >> 4;

    i32x4 bfrag[6][2];
#pragma unroll
    for (int j = 0; j < 6; ++j)
#pragma unroll
        for (int s = 0; s < 2; ++s)
            bfrag[j][s] = *(const i32x4*)(wq + (j * 16 + m) * 128 + s * 64 + q * 16);

    i32x4 acc[6];
#pragma unroll
    for (int j = 0; j < 6; ++j) {
        int bv = bias[j * 16 + m];
        acc[j] = (i32x4){bv, bv, bv, bv};
    }

    __syncthreads();

#pragma unroll
    for (int s = 0; s < 2; ++s) {
        i32x4 a = *(const i32x4*)(lds + (wid * 16 + m) * 36 + s * 16 + q * 4);
#pragma unroll
        for (int j = 0; j < 6; ++j)
            acc[j] = __builtin_amdgcn_mfma_i32_16x16x64_i8(a, bfrag[j][s], acc[j], 0, 0, 0);
    }

#pragma unroll
    for (int j = 0; j < 6; ++j) {
        int oc = j * 16 + m;
#pragma unroll
        for (int r = 0; r < 4; ++r) {
            int site = siteBase + wid * 16 + q * 4 + r;
            float v = floorf((float)acc[j][r] * 2e-3f);
            v = fminf(fmaxf(v, 0.0f), 127.0f);
            out[(size_t)site * 96 + oc] = (signed char)v;
        }
    }
}

// ---------------- implicit-GEMM 32x32x32 MFMA conv/FC, padded act, LDS-staged B ----------------
// act: physically padded NHWC int8 (PH x PW, halo zeros). Branchless inner loop.
// wqf: fragment-major [Cout/32][KSTEPS][64][16], K tap-major (step = tap*CP + cpair).
// Groups of GSTEP k-steps (GSTEP <= CP, CP % GSTEP == 0): sub-tap staging keeps LDS
// small enough for 3 blocks/CU (__launch_bounds__(256,3) -> 12 waves/CU latency hiding).
// OCT=2 x SITES=2 register tile: acc = 64 AGPRs -> ~140 total regs/wave.
// grid.x = M/(128*SITES), grid.y = Cout/(OCT*32).

template <int KS, int CIN, int OCT, int SITES, int GSTEP, int OH, int OW>
__launch_bounds__(256, 3)
__global__ void conv_mfma32(const signed char* __restrict__ act,
                            const signed char* __restrict__ wqf,
                            const int* __restrict__ bias,
                            signed char* __restrict__ out,
                            int PH, int PW, int outImg, int outRow, int outOff,
                            int Cout, float M) {
    constexpr int CP = CIN / 32;
    constexpr int TPG = CP / GSTEP;               // sub-groups per tap
    constexpr int KSTEPS = KS * KS * CP;
    constexpr int NG = KS * KS * TPG;
    constexpr int CHUNK = OCT * GSTEP * 1024;
    constexpr int UNITS = OCT * GSTEP;
    static_assert(CIN % 32 == 0, "CIN multiple of 32");
    static_assert(CP % GSTEP == 0, "GSTEP must divide CP");

    __shared__ signed char lds[2 * CHUNK];

    int lane = threadIdx.x & 63;
    int wid = threadIdx.x >> 6;
    int m32 = lane & 31;
    int q2 = lane >> 5;
    int waveBase = blockIdx.x * (SITES * 128) + wid * (SITES * 32);
    int oc0 = blockIdx.y * (OCT * 32);

    const signed char* baseA[SITES];
#pragma unroll
    for (int s = 0; s < SITES; ++s) {
        int site = waveBase + s * 32 + m32;
        int ox = site % OW;
        int t = site / OW;
        int oy = t % OH;
        int n = t / OH;
        baseA[s] = act + ((size_t)(n * PH + oy) * PW + ox) * CIN + q2 * 16;
    }

    i32x16 acc[SITES][OCT];
#pragma unroll
    for (int j = 0; j < OCT; ++j) {
        int bv = bias[oc0 + j * 32 + m32];
#pragma unroll
        for (int s = 0; s < SITES; ++s)
#pragma unroll
            for (int r = 0; r < 16; ++r)
                acc[s][j][r] = bv;
    }

    const signed char* wblk = wqf + (size_t)(blockIdx.y * OCT) * KSTEPS * 1024;

    auto stage = [&](int buf, int g) {
#pragma unroll
        for (int t = 0; t < (UNITS + 3) / 4; ++t) {
            int u = t * 4 + wid;                  // 1KB unit: u = j*GSTEP + s
            if (u < UNITS) {
                int j = u / GSTEP;
                int s = u - j * GSTEP;
                const signed char* gsrc =
                    wblk + (((size_t)(j * KSTEPS + g * GSTEP + s)) << 10) + lane * 16;
                async_cp16(gsrc, lds + buf * CHUNK + (u << 10));
            }
        }
    };

    stage(0, 0);

    int ty = 0, tx = 0, sub = 0;
    for (int g = 0; g < NG; ++g) {
        __syncthreads();
        if (g + 1 < NG) stage((g + 1) & 1, g + 1);

        int aoff = (ty * PW + tx) * CIN + sub * (GSTEP * 32);
        const signed char* ap[SITES];
#pragma unroll
        for (int s = 0; s < SITES; ++s) ap[s] = baseA[s] + aoff;

        const signed char* lb = lds + (g & 1) * CHUNK + lane * 16;
#pragma unroll
        for (int cp = 0; cp < GSTEP; ++cp) {
            i32x4 a[SITES];
#pragma unroll
            for (int s = 0; s < SITES; ++s)
                a[s] = *(const i32x4*)(ap[s] + cp * 32);   // unconditional: halo is zero
#pragma unroll
            for (int j = 0; j < OCT; ++j) {
                i32x4 b = *(const i32x4*)(lb + ((j * GSTEP + cp) << 10));
#pragma unroll
                for (int s = 0; s < SITES; ++s)
                    acc[s][j] = __builtin_amdgcn_mfma_i32_32x32x32_i8(a[s], b, acc[s][j], 0, 0, 0);
            }
        }
        ++sub;
        if (sub == TPG) { sub = 0; ++tx; if (tx == KS) { tx = 0; ++ty; } }
    }

    // D layout: col(oc) = lane&31, row(site) = (r&3) + 8*(r>>2) + 4*q2
#pragma unroll
    for (int s = 0; s < SITES; ++s) {
#pragma unroll
        for (int r = 0; r < 16; ++r) {
            int row = (r & 3) + 8 * (r >> 2) + 4 * q2;
            int site = waveBase + s * 32 + row;
            int ox = site % OW;
            int t = site / OW;
            int oy = t % OH;
            int n = t / OH;
            size_t base = (size_t)n * outImg + oy * outRow + ox * Cout + outOff + oc0 + m32;
#pragma unroll
            for (int j = 0; j < OCT; ++j) {
                float v = floorf((float)acc[s][j][r] * M);
                v = fminf(fmaxf(v, 0.0f), 127.0f);
                out[base + j * 32] = (signed char)v;
            }
        }
    }
}

// ---------------- maxpool 3x3 stride 2, NHWC, padded output (halo written as 0) ----------------

__global__ void qmaxpool(const signed char* __restrict__ in, signed char* __restrict__ out,
                         int N, int H, int W, int C4,
                         int OH, int OW, int OHp, int OWp, int opad, int total) {
    int idx = blockIdx.x * blockDim.x + threadIdx.x;
    if (idx >= total) return;
    int cc = idx % C4;
    int t = idx / C4;
    int oxp = t % OWp; t /= OWp;
    int oyp = t % OHp;
    int n = t / OHp;
    int oy = oyp - opad, ox = oxp - opad;
    int res = 0;
    if ((unsigned)oy < (unsigned)OH && (unsigned)ox < (unsigned)OW) {
        const int* ip = (const int*)in;
        int base = ((n * H + oy * 2) * W + ox * 2) * C4 + cc;
        int m0 = -128, m1 = -128, m2 = -128, m3 = -128;
#pragma unroll
        for (int dy = 0; dy < 3; ++dy)
#pragma unroll
            for (int dx = 0; dx < 3; ++dx) {
                int v = ip[base + (dy * W + dx) * C4];
                m0 = max(m0, (int)(signed char)(v & 0xff));
                m1 = max(m1, (int)(signed char)((v >> 8) & 0xff));
                m2 = max(m2, (int)(signed char)((v >> 16) & 0xff));
                m3 = max(m3, (int)(signed char)(v >> 24));
            }
        res = (m0 & 0xff) | ((m1 & 0xff) << 8) | ((m2 & 0xff) << 16) | (m3 << 24);
    }
    ((int*)out)[idx] = res;
}

// ---------------- global avg pool over 3x3 + floor: [512,3,3,256] -> [512,256] ----------------

__global__ void qgap(const signed char* __restrict__ in, signed char* __restrict__ out) {
    int idx = blockIdx.x * blockDim.x + threadIdx.x;
    if (idx >= 512 * 256) return;
    int c = idx & 255;
    int n = idx >> 8;
    const signed char* p = in + n * 9 * 256 + c;
    int s = 0;
#pragma unroll
    for (int k = 0; k < 9; ++k) s += p[k * 256];
    out[idx] = (signed char)(s / 9);
}

// ---------------- final FC (no relu), fp32 out: one wave per (b,o) ----------------

__global__ void qfc3_wave(const signed char* __restrict__ act,
                          const signed char* __restrict__ wq,
                          const int* __restrict__ bias,
                          float* __restrict__ out) {
    int gid = blockIdx.x * blockDim.x + threadIdx.x;
    int wave = gid >> 6;
    int lane = gid & 63;
    if (wave >= 512 * 10) return;
    int o = wave % 10;
    int b = wave / 10;
    const int* aI = (const int*)act + b * 1024;
    const int* wI = (const int*)wq + o * 1024;
    int acc = 0;
#pragma unroll
    for (int it = 0; it < 16; ++it) {
        int k = it * 64 + lane;
        acc = dot4(aI[k], wI[k], acc);
    }
#pragma unroll
    for (int s = 32; s; s >>= 1) acc += __shfl_xor(acc, s);
    if (lane == 0) {
        float v = floorf((float)(acc + bias[o]) * 2e-4f);
        v = fminf(fmaxf(v, -128.0f), 127.0f);
        out[b * 10 + o] = v;
    }
}

// ---------------- launch ----------------

#define LAUNCH(kern, n, ...) kern<<<dim3(((n) + 255) / 256), dim3(256), 0, stream>>>(__VA_ARGS__)

extern "C" void kernel_launch(void* const* d_in, const int* in_sizes, int n_in,
                              void* d_out, int out_size, void* d_ws, size_t ws_size,
                              hipStream_t stream) {
    const float* x   = (const float*)d_in[0];
    const float* w1  = (const float*)d_in[1];
    const float* b1  = (const float*)d_in[2];
    const float* w2  = (const float*)d_in[3];
    const float* b2  = (const float*)d_in[4];
    const float* w3  = (const float*)d_in[5];
    const float* b3  = (const float*)d_in[6];
    const float* w4  = (const float*)d_in[7];
    const float* b4  = (const float*)d_in[8];
    const float* w5  = (const float*)d_in[9];
    const float* b5  = (const float*)d_in[10];
    const float* wf1 = (const float*)d_in[11];
    const float* bf1 = (const float*)d_in[12];
    const float* wf2 = (const float*)d_in[13];
    const float* bf2 = (const float*)d_in[14];
    const float* wf3 = (const float*)d_in[15];
    const float* bf3 = (const float*)d_in[16];
    float* out = (float*)d_out;

    char* ws = (char*)d_ws;
    size_t off = 0;
    auto A = [&](size_t sz) -> size_t {
        size_t o = off;
        off += (sz + 255) & ~(size_t)255;
        return o;
    };

    size_t wq1  = A(96 * 128);
    size_t wq2  = A((size_t)8 * 75 * 1024);
    size_t wq3  = A((size_t)12 * 72 * 1024);
    size_t wq4  = A((size_t)12 * 108 * 1024);
    size_t wq5  = A((size_t)8 * 108 * 1024);
    size_t wqf1 = A((size_t)128 * 8 * 1024);
    size_t wqf2 = A((size_t)128 * 128 * 1024);
    size_t wqf3 = A(10 * 4096);
    size_t bq1  = A(96 * 4);
    size_t bq2  = A(256 * 4);
    size_t bq3  = A(384 * 4);
    size_t bq4  = A(384 * 4);
    size_t bq5  = A(256 * 4);
    size_t bqf1 = A(4096 * 4);
    size_t bqf2 = A(4096 * 4);
    size_t bqf3 = A(10 * 4);
    size_t bufQ = A(2097152);                  // quantized input [512,32,32,4]
    size_t bufR1 = A(50331648);                // C1 -> C2 -> {C5, P3, G, F1, F2, C4}
    size_t bufR2 = A(17743872);                // P1 [512,19,19,96] -> C3 [512,9,9,384]
    size_t bufR3 = A(10616832);                // P2 [512,9,9,256]
    if (off > ws_size) return;

    signed char* W1 = (signed char*)(ws + wq1);
    signed char* W2 = (signed char*)(ws + wq2);
    signed char* W3 = (signed char*)(ws + wq3);
    signed char* W4 = (signed char*)(ws + wq4);
    signed char* W5 = (signed char*)(ws + wq5);
    signed char* WF1 = (signed char*)(ws + wqf1);
    signed char* WF2 = (signed char*)(ws + wqf2);
    signed char* WF3 = (signed char*)(ws + wqf3);
    int* B1 = (int*)(ws + bq1);
    int* B2 = (int*)(ws + bq2);
    int* B3 = (int*)(ws + bq3);
    int* B4 = (int*)(ws + bq4);
    int* B5 = (int*)(ws + bq5);
    int* BF1 = (int*)(ws + bqf1);
    int* BF2 = (int*)(ws + bqf2);
    int* BF3 = (int*)(ws + bqf3);

    signed char* Q  = (signed char*)(ws + bufQ);
    signed char* C1 = (signed char*)(ws + bufR1);             // [512,32,32,96]
    signed char* C2 = (signed char*)(ws + bufR1);             // [512,15,15,256] (C1 dead)
    signed char* C5 = (signed char*)(ws + bufR1);             // [512,7,7,256]  (C2 dead)
    signed char* P3 = (signed char*)(ws + bufR1 + 7340032);   // [512,3,3,256]
    signed char* G  = (signed char*)(ws + bufR1 + 9437184);   // [512,256]
    signed char* F1 = (signed char*)(ws + bufR1 + 10485760);  // [512,4096]
    signed char* F2 = (signed char*)(ws + bufR1 + 13631488);  // [512,4096]
    signed char* C4 = (signed char*)(ws + bufR1 + 31457280);  // [512,9,9,384] padded
    signed char* P1 = (signed char*)(ws + bufR2);             // [512,19,19,96] padded
    signed char* C3 = (signed char*)(ws + bufR2);             // [512,9,9,384] padded (P1 dead)
    signed char* P2 = (signed char*)(ws + bufR3);             // [512,9,9,256] padded

    // ---- weight/bias conversion ----
    LAUNCH(cvt_w1, 96 * 128, w1, W1);
    LAUNCH(cvt_w_frag32, 8 * 75 * 1024, w2, W2, 256, 96, 25, 3, 75);
    LAUNCH(cvt_w_frag32, 12 * 72 * 1024, w3, W3, 384, 256, 9, 8, 72);
    LAUNCH(cvt_w_frag32, 12 * 108 * 1024, w4, W4, 384, 384, 9, 12, 108);
    LAUNCH(cvt_w_frag32, 8 * 108 * 1024, w5, W5, 256, 384, 9, 12, 108);
    LAUNCH(cvt_w_frag32, 128 * 8 * 1024, wf1, WF1, 4096, 256, 1, 8, 8);
    LAUNCH(cvt_w_frag32, 128 * 128 * 1024, wf2, WF2, 4096, 4096, 1, 128, 128);
    LAUNCH(cvt_i8, 10 * 4096, wf3, WF3, 10 * 4096);
    LAUNCH(cvt_i32, 96, b1, B1, 96);
    LAUNCH(cvt_i32, 256, b2, B2, 256);
    LAUNCH(cvt_i32, 384, b3, B3, 384);
    LAUNCH(cvt_i32, 384, b4, B4, 384);
    LAUNCH(cvt_i32, 256, b5, B5, 256);
    LAUNCH(cvt_i32, 4096, bf1, BF1, 4096);
    LAUNCH(cvt_i32, 4096, bf2, BF2, 4096);
    LAUNCH(cvt_i32, 10, bf3, BF3, 10);

    // ---- forward ----
    LAUNCH(quantize_in, 512 * 1024, x, Q, 512 * 1024);

    // conv1: Q -> C1 [512,32,32,96]
    conv1_mfma<<<dim3(512 * 1024 / 64), dim3(256), 0, stream>>>(Q, W1, B1, C1);

    // pool1: C1 -> P1 padded [512,19,19,96] (halo zeros)
    LAUNCH(qmaxpool, 512 * 19 * 19 * 24, C1, P1, 512, 32, 32, 24, 15, 15, 19, 19, 2,
           512 * 19 * 19 * 24);

    // conv2: P1 -> C2 [512,15,15,256]; GSTEP=3 (=CP), NG=25, LDS 12 KB
    conv_mfma32<5, 96, 2, 2, 3, 15, 15><<<dim3(450, 4), dim3(256), 0, stream>>>(
        P1, W2, B2, C2, 19, 19, 225 * 256, 15 * 256, 0, 256, 4e-4f);

    // pool2: C2 -> P2 padded [512,9,9,256]
    LAUNCH(qmaxpool, 512 * 9 * 9 * 64, C2, P2, 512, 15, 15, 64, 7, 7, 9, 9, 1,
           512 * 9 * 9 * 64);

    // zero halos of conv3/conv4 padded outputs
    hipMemsetAsync(C3, 0, 512 * 9 * 9 * 384, stream);
    hipMemsetAsync(C4, 0, 512 * 9 * 9 * 384, stream);

    // conv3: P2 -> C3 padded [512,9,9,384]; GSTEP=4 (CP=8), NG=18, LDS 16 KB
    conv_mfma32<3, 256, 2, 2, 4, 7, 7><<<dim3(98, 6), dim3(256), 0, stream>>>(
        P2, W3, B3, C3, 9, 9, 81 * 384, 9 * 384, 10 * 384, 384, 2e-4f);

    // conv4: C3 -> C4 padded [512,9,9,384]; GSTEP=4 (CP=12), NG=27
    conv_mfma32<3, 384, 2, 2, 4, 7, 7><<<dim3(98, 6), dim3(256), 0, stream>>>(
        C3, W4, B4, C4, 9, 9, 81 * 384, 9 * 384, 10 * 384, 384, 2e-4f);

    // conv5: C4 -> C5 [512,7,7,256]; GSTEP=4 (CP=12), NG=27
    conv_mfma32<3, 384, 2, 2, 4, 7, 7><<<dim3(98, 4), dim3(256), 0, stream>>>(
        C4, W5, B5, C5, 9, 9, 49 * 256, 7 * 256, 0, 256, 2e-4f);

    // pool3: C5 -> P3 [512,3,3,256] (unpadded)
    LAUNCH(qmaxpool, 512 * 3 * 3 * 64, C5, P3, 512, 7, 7, 64, 3, 3, 3, 3, 0,
           512 * 3 * 3 * 64);

    // gap: P3 -> G [512,256]
    LAUNCH(qgap, 512 * 256, P3, G);

    // fc1: G -> F1 [512,4096]; GSTEP=8 (CP=8), NG=1
    conv_mfma32<1, 256, 2, 2, 8, 1, 1><<<dim3(2, 64), dim3(256), 0, stream>>>(
        G, WF1, BF1, F1, 1, 1, 4096, 4096, 0, 4096, 1e-3f);

    // fc2: F1 -> F2 [512,4096]; GSTEP=8 (CP=128), NG=16, LDS 32 KB
    conv_mfma32<1, 4096, 2, 2, 8, 1, 1><<<dim3(2, 64), dim3(256), 0, stream>>>(
        F1, WF2, BF2, F2, 1, 1, 4096, 4096, 0, 4096, 2e-4f);

    // fc3: F2 -> out [512,10] fp32
    qfc3_wave<<<dim3(512 * 10 * 64 / 256), dim3(256), 0, stream>>>(F2, WF3, BF3, out);
}

// Round 10
// 629.477 us; speedup vs baseline: 1.1195x; 1.1195x over previous
//
#include <hip/hip_runtime.h>

#define DEV_INLINE __device__ __forceinline__

typedef int i32x4 __attribute__((ext_vector_type(4)));
typedef int i32x16 __attribute__((ext_vector_type(16)));

DEV_INLINE int dot4(int a, int b, int c) {
#if __has_builtin(__builtin_amdgcn_sdot4)
    return __builtin_amdgcn_sdot4(a, b, c, false);
#else
    return c
        + (int)(signed char)(a)       * (int)(signed char)(b)
        + (int)(signed char)(a >> 8)  * (int)(signed char)(b >> 8)
        + (int)(signed char)(a >> 16) * (int)(signed char)(b >> 16)
        + (int)(signed char)(a >> 24) * (int)(signed char)(b >> 24);
#endif
}

typedef __attribute__((address_space(1))) const unsigned int guint;
typedef __attribute__((address_space(3))) unsigned int luint;

DEV_INLINE void async_cp16(const signed char* g, signed char* l) {
    __builtin_amdgcn_global_load_lds((guint*)g, (luint*)l, 16, 0, 0);
}

// ---------------- conversion kernels ----------------

// Repack weights to 32-wide MFMA B-fragment-major order, K tap-major:
//   step = tap*CP + cpair; lane holds B[oc%32][c = cpair*32 + (lane>>5)*16 + j of tap]
__global__ void cvt_w_frag32(const float* __restrict__ w, signed char* __restrict__ o,
                             int O, int I, int KK, int CP, int KSTEPS) {
    int idx = blockIdx.x * blockDim.x + threadIdx.x;
    int total = (O >> 5) * KSTEPS * 1024;
    if (idx >= total) return;
    int j = idx & 15;
    int lane = (idx >> 4) & 63;
    int step = (idx >> 10) % KSTEPS;
    int tile = idx / (KSTEPS << 10);
    int oc = tile * 32 + (lane & 31);
    int tap = step / CP;
    int cpair = step - tap * CP;
    int c = cpair * 32 + ((lane >> 5) << 4) + j;
    float v = w[((size_t)oc * I + c) * KK + tap];
    o[idx] = (signed char)(int)v;
}

// conv1 weights: OIHW [96][3][5][5] fp32 -> [96][128] int8, byte [oc][tap*4+c]
__global__ void cvt_w1(const float* __restrict__ w, signed char* __restrict__ o) {
    int idx = blockIdx.x * blockDim.x + threadIdx.x;
    if (idx >= 96 * 128) return;
    int b = idx & 127;
    int oc = idx >> 7;
    int tap = b >> 2;
    int c = b & 3;
    float v = (tap < 25 && c < 3) ? w[(oc * 3 + c) * 25 + tap] : 0.0f;
    o[idx] = (signed char)(int)v;
}

__global__ void cvt_i8(const float* __restrict__ w, signed char* __restrict__ o, int n) {
    int idx = blockIdx.x * blockDim.x + threadIdx.x;
    if (idx < n) o[idx] = (signed char)(int)w[idx];
}

__global__ void cvt_i32(const float* __restrict__ b, int* __restrict__ o, int n) {
    int idx = blockIdx.x * blockDim.x + threadIdx.x;
    if (idx < n) o[idx] = (int)b[idx];
}

// ---------------- quantize input: NCHW fp32 [512,3,32,32] -> NHWC int8 [512,32,32,4] ----------------

__global__ void quantize_in(const float* __restrict__ x, signed char* __restrict__ q, int total) {
    int idx = blockIdx.x * blockDim.x + threadIdx.x;
    if (idx >= total) return;
    int hw = idx & 1023;
    int n = idx >> 10;
    const float* xp = x + n * 3072 + hw;
    int b[4];
#pragma unroll
    for (int c = 0; c < 3; ++c) {
        float v = rintf(xp[c * 1024] / 0.05f);
        v = fminf(fmaxf(v, -128.0f), 127.0f);
        b[c] = (int)v;
    }
    b[3] = 0;
    int packed = (b[0] & 0xff) | ((b[1] & 0xff) << 8) | ((b[2] & 0xff) << 16) | (b[3] << 24);
    ((int*)q)[idx] = packed;
}

// ---------------- conv1 MFMA with LDS im2col (16x16x64, Cin=4) ----------------

__global__ void conv1_mfma(const signed char* __restrict__ act,
                           const signed char* __restrict__ wq,
                           const int* __restrict__ bias,
                           signed char* __restrict__ out) {
    __shared__ int lds[64 * 36];

    int tid = threadIdx.x;
    int lane = tid & 63;
    int wid = tid >> 6;
    int siteBase = blockIdx.x * 64;

    {
        int site_local = tid >> 2;
        int g = tid & 3;
        int site = siteBase + site_local;
        int ox = site & 31;
        int oy = (site >> 5) & 31;
        int n = site >> 10;
        const int* aI = (const int*)act;
        int* dst = lds + site_local * 36 + g * 8;
#pragma unroll
        for (int j = 0; j < 8; ++j) {
            int tap = g * 8 + j;
            int v = 0;
            if (tap < 25) {
                int ky = tap / 5;
                int kx = tap - ky * 5;
                int iy = oy - 2 + ky;
                int ix = ox - 2 + kx;
                if ((unsigned)iy < 32u && (unsigned)ix < 32u)
                    v = aI[(n << 10) + (iy << 5) + ix];
            }
            dst[j] = v;
        }
    }

    int m = lane & 15;
    int q = lane >> 4;

    i32x4 bfrag[6][2];
#pragma unroll
    for (int j = 0; j < 6; ++j)
#pragma unroll
        for (int s = 0; s < 2; ++s)
            bfrag[j][s] = *(const i32x4*)(wq + (j * 16 + m) * 128 + s * 64 + q * 16);

    i32x4 acc[6];
#pragma unroll
    for (int j = 0; j < 6; ++j) {
        int bv = bias[j * 16 + m];
        acc[j] = (i32x4){bv, bv, bv, bv};
    }

    __syncthreads();

#pragma unroll
    for (int s = 0; s < 2; ++s) {
        i32x4 a = *(const i32x4*)(lds + (wid * 16 + m) * 36 + s * 16 + q * 4);
#pragma unroll
        for (int j = 0; j < 6; ++j)
            acc[j] = __builtin_amdgcn_mfma_i32_16x16x64_i8(a, bfrag[j][s], acc[j], 0, 0, 0);
    }

#pragma unroll
    for (int j = 0; j < 6; ++j) {
        int oc = j * 16 + m;
#pragma unroll
        for (int r = 0; r < 4; ++r) {
            int site = siteBase + wid * 16 + q * 4 + r;
            float v = floorf((float)acc[j][r] * 2e-3f);
            v = fminf(fmaxf(v, 0.0f), 127.0f);
            out[(size_t)site * 96 + oc] = (signed char)v;
        }
    }
}

// ---------------- implicit-GEMM 32x32x32 MFMA conv/FC, padded act, LDS-staged B ----------------
// act: physically padded NHWC int8 (halo zeros), row stride PW (template), image stride
// imgStride (runtime). wqf: fragment-major [Cout/32][KSTEPS][64][16], K tap-major.
// Fully-unrolled K-loop: all tap/channel/LDS offsets are compile-time constants.
// Groups of GSTEP k-steps (any divisor of KSTEPS), double-buffered async DMA; one
// barrier per group with OCT*SITES*GSTEP MFMAs/wave of cover.
// grid.x = M/(128*SITES), grid.y = Cout/(OCT*32).

template <int KS, int CIN, int OCT, int SITES, int GSTEP, int OH, int OW, int PW>
__launch_bounds__(256, 2)
__global__ void conv_mfma32(const signed char* __restrict__ act,
                            const signed char* __restrict__ wqf,
                            const int* __restrict__ bias,
                            signed char* __restrict__ out,
                            int imgStride, int outImg, int outRow, int outOff,
                            int Cout, float M) {
    constexpr int CP = CIN / 32;
    constexpr int KSTEPS = KS * KS * CP;
    static_assert(KSTEPS % GSTEP == 0, "GSTEP must divide KSTEPS");
    constexpr int NG = KSTEPS / GSTEP;
    constexpr int UNITS = OCT * GSTEP;
    static_assert(UNITS % 4 == 0, "stage units split across 4 waves");
    constexpr int CHUNK = UNITS * 1024;

    __shared__ signed char lds[2 * CHUNK];

    int lane = threadIdx.x & 63;
    int wid = threadIdx.x >> 6;
    int m32 = lane & 31;
    int q2 = lane >> 5;
    int waveBase = blockIdx.x * (SITES * 128) + wid * (SITES * 32);
    int oc0 = blockIdx.y * (OCT * 32);

    const signed char* baseA[SITES];
#pragma unroll
    for (int s = 0; s < SITES; ++s) {
        int site = waveBase + s * 32 + m32;
        int ox = site % OW;
        int t = site / OW;
        int oy = t % OH;
        int n = t / OH;
        baseA[s] = act + ((size_t)n * imgStride + oy * PW + ox) * CIN + q2 * 16;
    }

    i32x16 acc[SITES][OCT];
#pragma unroll
    for (int j = 0; j < OCT; ++j) {
        int bv = bias[oc0 + j * 32 + m32];
#pragma unroll
        for (int s = 0; s < SITES; ++s)
#pragma unroll
            for (int r = 0; r < 16; ++r)
                acc[s][j][r] = bv;
    }

    const signed char* wblk = wqf + (size_t)(blockIdx.y * OCT) * KSTEPS * 1024;

    auto stage = [&](int buf, int g) {
#pragma unroll
        for (int t = 0; t < UNITS / 4; ++t) {
            int u = t * 4 + wid;                  // 1KB unit: u = j*GSTEP + s
            int j = u / GSTEP;
            int s = u - j * GSTEP;
            const signed char* gsrc =
                wblk + (((size_t)(j * KSTEPS + g * GSTEP + s)) << 10) + lane * 16;
            async_cp16(gsrc, lds + buf * CHUNK + (u << 10));
        }
    };

    stage(0, 0);

#pragma unroll
    for (int g = 0; g < NG; ++g) {
        __syncthreads();
        if (g + 1 < NG) stage((g + 1) & 1, g + 1);

        const signed char* lb = lds + (g & 1) * CHUNK + lane * 16;
#pragma unroll
        for (int cp = 0; cp < GSTEP; ++cp) {
            constexpr int dummy = 0; (void)dummy;
            int k16 = g * GSTEP + cp;             // compile-time (full unroll)
            int tap = k16 / CP;
            int cpair = k16 - tap * CP;
            int ty = tap / KS;
            int tx = tap - ty * KS;
            int aoff = (ty * PW + tx) * CIN + cpair * 32;   // constant-folded

            i32x4 a[SITES];
#pragma unroll
            for (int s = 0; s < SITES; ++s)
                a[s] = *(const i32x4*)(baseA[s] + aoff);    // unconditional: halo is zero
#pragma unroll
            for (int j = 0; j < OCT; ++j) {
                i32x4 b = *(const i32x4*)(lb + ((j * GSTEP + cp) << 10));
#pragma unroll
                for (int s = 0; s < SITES; ++s)
                    acc[s][j] = __builtin_amdgcn_mfma_i32_32x32x32_i8(a[s], b, acc[s][j], 0, 0, 0);
            }
        }
    }

    // D layout: col(oc) = lane&31, row(site) = (r&3) + 8*(r>>2) + 4*q2
#pragma unroll
    for (int s = 0; s < SITES; ++s) {
#pragma unroll
        for (int r = 0; r < 16; ++r) {
            int row = (r & 3) + 8 * (r >> 2) + 4 * q2;
            int site = waveBase + s * 32 + row;
            int ox = site % OW;
            int t = site / OW;
            int oy = t % OH;
            int n = t / OH;
            size_t base = (size_t)n * outImg + oy * outRow + ox * Cout + outOff + oc0 + m32;
#pragma unroll
            for (int j = 0; j < OCT; ++j) {
                float v = floorf((float)acc[s][j][r] * M);
                v = fminf(fmaxf(v, 0.0f), 127.0f);
                out[base + j * 32] = (signed char)v;
            }
        }
    }
}

// ---------------- maxpool 3x3 stride 2, NHWC, padded output (halo written as 0) ----------------

__global__ void qmaxpool(const signed char* __restrict__ in, signed char* __restrict__ out,
                         int N, int H, int W, int C4,
                         int OH, int OW, int OHp, int OWp, int opad, int total) {
    int idx = blockIdx.x * blockDim.x + threadIdx.x;
    if (idx >= total) return;
    int cc = idx % C4;
    int t = idx / C4;
    int oxp = t % OWp; t /= OWp;
    int oyp = t % OHp;
    int n = t / OHp;
    int oy = oyp - opad, ox = oxp - opad;
    int res = 0;
    if ((unsigned)oy < (unsigned)OH && (unsigned)ox < (unsigned)OW) {
        const int* ip = (const int*)in;
        int base = ((n * H + oy * 2) * W + ox * 2) * C4 + cc;
        int m0 = -128, m1 = -128, m2 = -128, m3 = -128;
#pragma unroll
        for (int dy = 0; dy < 3; ++dy)
#pragma unroll
            for (int dx = 0; dx < 3; ++dx) {
                int v = ip[base + (dy * W + dx) * C4];
                m0 = max(m0, (int)(signed char)(v & 0xff));
                m1 = max(m1, (int)(signed char)((v >> 8) & 0xff));
                m2 = max(m2, (int)(signed char)((v >> 16) & 0xff));
                m3 = max(m3, (int)(signed char)(v >> 24));
            }
        res = (m0 & 0xff) | ((m1 & 0xff) << 8) | ((m2 & 0xff) << 16) | (m3 << 24);
    }
    ((int*)out)[idx] = res;
}

// ---------------- global avg pool over 3x3 + floor: [512,3,3,256] -> [512,256] ----------------

__global__ void qgap(const signed char* __restrict__ in, signed char* __restrict__ out) {
    int idx = blockIdx.x * blockDim.x + threadIdx.x;
    if (idx >= 512 * 256) return;
    int c = idx & 255;
    int n = idx >> 8;
    const signed char* p = in + n * 9 * 256 + c;
    int s = 0;
#pragma unroll
    for (int k = 0; k < 9; ++k) s += p[k * 256];
    out[idx] = (signed char)(s / 9);
}

// ---------------- final FC (no relu), fp32 out: one wave per (b,o) ----------------

__global__ void qfc3_wave(const signed char* __restrict__ act,
                          const signed char* __restrict__ wq,
                          const int* __restrict__ bias,
                          float* __restrict__ out) {
    int gid = blockIdx.x * blockDim.x + threadIdx.x;
    int wave = gid >> 6;
    int lane = gid & 63;
    if (wave >= 512 * 10) return;
    int o = wave % 10;
    int b = wave / 10;
    const int* aI = (const int*)act + b * 1024;
    const int* wI = (const int*)wq + o * 1024;
    int acc = 0;
#pragma unroll
    for (int it = 0; it < 16; ++it) {
        int k = it * 64 + lane;
        acc = dot4(aI[k], wI[k], acc);
    }
#pragma unroll
    for (int s = 32; s; s >>= 1) acc += __shfl_xor(acc, s);
    if (lane == 0) {
        float v = floorf((float)(acc + bias[o]) * 2e-4f);
        v = fminf(fmaxf(v, -128.0f), 127.0f);
        out[b * 10 + o] = v;
    }
}

// ---------------- launch ----------------

#define LAUNCH(kern, n, ...) kern<<<dim3(((n) + 255) / 256), dim3(256), 0, stream>>>(__VA_ARGS__)

extern "C" void kernel_launch(void* const* d_in, const int* in_sizes, int n_in,
                              void* d_out, int out_size, void* d_ws, size_t ws_size,
                              hipStream_t stream) {
    const float* x   = (const float*)d_in[0];
    const float* w1  = (const float*)d_in[1];
    const float* b1  = (const float*)d_in[2];
    const float* w2  = (const float*)d_in[3];
    const float* b2  = (const float*)d_in[4];
    const float* w3  = (const float*)d_in[5];
    const float* b3  = (const float*)d_in[6];
    const float* w4  = (const float*)d_in[7];
    const float* b4  = (const float*)d_in[8];
    const float* w5  = (const float*)d_in[9];
    const float* b5  = (const float*)d_in[10];
    const float* wf1 = (const float*)d_in[11];
    const float* bf1 = (const float*)d_in[12];
    const float* wf2 = (const float*)d_in[13];
    const float* bf2 = (const float*)d_in[14];
    const float* wf3 = (const float*)d_in[15];
    const float* bf3 = (const float*)d_in[16];
    float* out = (float*)d_out;

    char* ws = (char*)d_ws;
    size_t off = 0;
    auto A = [&](size_t sz) -> size_t {
        size_t o = off;
        off += (sz + 255) & ~(size_t)255;
        return o;
    };

    size_t wq1  = A(96 * 128);
    size_t wq2  = A((size_t)8 * 75 * 1024);
    size_t wq3  = A((size_t)12 * 72 * 1024);
    size_t wq4  = A((size_t)12 * 108 * 1024);
    size_t wq5  = A((size_t)8 * 108 * 1024);
    size_t wqf1 = A((size_t)128 * 8 * 1024);
    size_t wqf2 = A((size_t)128 * 128 * 1024);
    size_t wqf3 = A(10 * 4096);
    size_t bq1  = A(96 * 4);
    size_t bq2  = A(256 * 4);
    size_t bq3  = A(384 * 4);
    size_t bq4  = A(384 * 4);
    size_t bq5  = A(256 * 4);
    size_t bqf1 = A(4096 * 4);
    size_t bqf2 = A(4096 * 4);
    size_t bqf3 = A(10 * 4);
    size_t bufQ = A(2097152);                  // quantized input [512,32,32,4]
    size_t bufR1 = A(50331648);                // C1 -> C2 -> {C5, P3, G, F1, F2, C4}
    size_t bufR2 = A(17743872);                // P1 [512,19,19,96] -> C3 [512,9,9,384]
    size_t bufR3 = A(10616832);                // P2 [512,9,9,256]
    if (off > ws_size) return;

    signed char* W1 = (signed char*)(ws + wq1);
    signed char* W2 = (signed char*)(ws + wq2);
    signed char* W3 = (signed char*)(ws + wq3);
    signed char* W4 = (signed char*)(ws + wq4);
    signed char* W5 = (signed char*)(ws + wq5);
    signed char* WF1 = (signed char*)(ws + wqf1);
    signed char* WF2 = (signed char*)(ws + wqf2);
    signed char* WF3 = (signed char*)(ws + wqf3);
    int* B1 = (int*)(ws + bq1);
    int* B2 = (int*)(ws + bq2);
    int* B3 = (int*)(ws + bq3);
    int* B4 = (int*)(ws + bq4);
    int* B5 = (int*)(ws + bq5);
    int* BF1 = (int*)(ws + bqf1);
    int* BF2 = (int*)(ws + bqf2);
    int* BF3 = (int*)(ws + bqf3);

    signed char* Q  = (signed char*)(ws + bufQ);
    signed char* C1 = (signed char*)(ws + bufR1);             // [512,32,32,96]
    signed char* C2 = (signed char*)(ws + bufR1);             // [512,15,15,256] (C1 dead)
    signed char* C5 = (signed char*)(ws + bufR1);             // [512,7,7,256]  (C2 dead)
    signed char* P3 = (signed char*)(ws + bufR1 + 7340032);   // [512,3,3,256]
    signed char* G  = (signed char*)(ws + bufR1 + 9437184);   // [512,256]
    signed char* F1 = (signed char*)(ws + bufR1 + 10485760);  // [512,4096]
    signed char* F2 = (signed char*)(ws + bufR1 + 13631488);  // [512,4096]
    signed char* C4 = (signed char*)(ws + bufR1 + 31457280);  // [512,9,9,384] padded
    signed char* P1 = (signed char*)(ws + bufR2);             // [512,19,19,96] padded
    signed char* C3 = (signed char*)(ws + bufR2);             // [512,9,9,384] padded (P1 dead)
    signed char* P2 = (signed char*)(ws + bufR3);             // [512,9,9,256] padded

    // ---- weight/bias conversion ----
    LAUNCH(cvt_w1, 96 * 128, w1, W1);
    LAUNCH(cvt_w_frag32, 8 * 75 * 1024, w2, W2, 256, 96, 25, 3, 75);
    LAUNCH(cvt_w_frag32, 12 * 72 * 1024, w3, W3, 384, 256, 9, 8, 72);
    LAUNCH(cvt_w_frag32, 12 * 108 * 1024, w4, W4, 384, 384, 9, 12, 108);
    LAUNCH(cvt_w_frag32, 8 * 108 * 1024, w5, W5, 256, 384, 9, 12, 108);
    LAUNCH(cvt_w_frag32, 128 * 8 * 1024, wf1, WF1, 4096, 256, 1, 8, 8);
    LAUNCH(cvt_w_frag32, 128 * 128 * 1024, wf2, WF2, 4096, 4096, 1, 128, 128);
    LAUNCH(cvt_i8, 10 * 4096, wf3, WF3, 10 * 4096);
    LAUNCH(cvt_i32, 96, b1, B1, 96);
    LAUNCH(cvt_i32, 256, b2, B2, 256);
    LAUNCH(cvt_i32, 384, b3, B3, 384);
    LAUNCH(cvt_i32, 384, b4, B4, 384);
    LAUNCH(cvt_i32, 256, b5, B5, 256);
    LAUNCH(cvt_i32, 4096, bf1, BF1, 4096);
    LAUNCH(cvt_i32, 4096, bf2, BF2, 4096);
    LAUNCH(cvt_i32, 10, bf3, BF3, 10);

    // ---- forward ----
    LAUNCH(quantize_in, 512 * 1024, x, Q, 512 * 1024);

    // conv1: Q -> C1 [512,32,32,96]
    conv1_mfma<<<dim3(512 * 1024 / 64), dim3(256), 0, stream>>>(Q, W1, B1, C1);

    // pool1: C1 -> P1 padded [512,19,19,96] (halo zeros)
    LAUNCH(qmaxpool, 512 * 19 * 19 * 24, C1, P1, 512, 32, 32, 24, 15, 15, 19, 19, 2,
           512 * 19 * 19 * 24);

    // conv2: P1 -> C2 [512,15,15,256]; GSTEP=5, NG=15, LDS 40 KB, 40 MFMA/wave/barrier
    conv_mfma32<5, 96, 4, 2, 5, 15, 15, 19><<<dim3(450, 2), dim3(256), 0, stream>>>(
        P1, W2, B2, C2, 361, 225 * 256, 15 * 256, 0, 256, 4e-4f);

    // pool2: C2 -> P2 padded [512,9,9,256]
    LAUNCH(qmaxpool, 512 * 9 * 9 * 64, C2, P2, 512, 15, 15, 64, 7, 7, 9, 9, 1,
           512 * 9 * 9 * 64);

    // zero halos of conv3/conv4 padded outputs
    hipMemsetAsync(C3, 0, 512 * 9 * 9 * 384, stream);
    hipMemsetAsync(C4, 0, 512 * 9 * 9 * 384, stream);

    // conv3: P2 -> C3 padded [512,9,9,384]; GSTEP=6, NG=12, LDS 48 KB
    conv_mfma32<3, 256, 4, 2, 6, 7, 7, 9><<<dim3(98, 3), dim3(256), 0, stream>>>(
        P2, W3, B3, C3, 81, 81 * 384, 9 * 384, 10 * 384, 384, 2e-4f);

    // conv4: C3 -> C4 padded [512,9,9,384]; GSTEP=6, NG=18
    conv_mfma32<3, 384, 4, 2, 6, 7, 7, 9><<<dim3(98, 3), dim3(256), 0, stream>>>(
        C3, W4, B4, C4, 81, 81 * 384, 9 * 384, 10 * 384, 384, 2e-4f);

    // conv5: C4 -> C5 [512,7,7,256]; GSTEP=6, NG=18
    conv_mfma32<3, 384, 4, 2, 6, 7, 7, 9><<<dim3(98, 2), dim3(256), 0, stream>>>(
        C4, W5, B5, C5, 81, 49 * 256, 7 * 256, 0, 256, 2e-4f);

    // pool3: C5 -> P3 [512,3,3,256] (unpadded)
    LAUNCH(qmaxpool, 512 * 3 * 3 * 64, C5, P3, 512, 7, 7, 64, 3, 3, 3, 3, 0,
           512 * 3 * 3 * 64);

    // gap: P3 -> G [512,256]
    LAUNCH(qgap, 512 * 256, P3, G);

    // fc1: G -> F1 [512,4096]; GSTEP=4, NG=2, LDS 32 KB
    conv_mfma32<1, 256, 4, 2, 4, 1, 1, 1><<<dim3(2, 32), dim3(256), 0, stream>>>(
        G, WF1, BF1, F1, 1, 4096, 4096, 0, 4096, 1e-3f);

    // fc2: F1 -> F2 [512,4096]; GSTEP=4, NG=32, LDS 32 KB
    conv_mfma32<1, 4096, 4, 2, 4, 1, 1, 1><<<dim3(2, 32), dim3(256), 0, stream>>>(
        F1, WF2, BF2, F2, 1, 4096, 4096, 0, 4096, 2e-4f);

    // fc3: F2 -> out [512,10] fp32
    qfc3_wave<<<dim3(512 * 10 * 64 / 256), dim3(256), 0, stream>>>(F2, WF3, BF3, out);
}

// Round 11
// 606.585 us; speedup vs baseline: 1.1617x; 1.0377x over previous
//
#include <hip/hip_runtime.h>

#define DEV_INLINE __device__ __forceinline__

typedef int i32x4 __attribute__((ext_vector_type(4)));
typedef int i32x16 __attribute__((ext_vector_type(16)));

DEV_INLINE int dot4(int a, int b, int c) {
#if __has_builtin(__builtin_amdgcn_sdot4)
    return __builtin_amdgcn_sdot4(a, b, c, false);
#else
    return c
        + (int)(signed char)(a)       * (int)(signed char)(b)
        + (int)(signed char)(a >> 8)  * (int)(signed char)(b >> 8)
        + (int)(signed char)(a >> 16) * (int)(signed char)(b >> 16)
        + (int)(signed char)(a >> 24) * (int)(signed char)(b >> 24);
#endif
}

typedef __attribute__((address_space(1))) const unsigned int guint;
typedef __attribute__((address_space(3))) unsigned int luint;

DEV_INLINE void async_cp16(const signed char* g, signed char* l) {
    __builtin_amdgcn_global_load_lds((guint*)g, (luint*)l, 16, 0, 0);
}

// ---------------- conversion kernels ----------------

// Repack weights to 32-wide MFMA B-fragment-major order, K tap-major:
//   step = tap*CP + cpair; lane holds B[oc%32][c = cpair*32 + (lane>>5)*16 + j of tap]
__global__ void cvt_w_frag32(const float* __restrict__ w, signed char* __restrict__ o,
                             int O, int I, int KK, int CP, int KSTEPS) {
    int idx = blockIdx.x * blockDim.x + threadIdx.x;
    int total = (O >> 5) * KSTEPS * 1024;
    if (idx >= total) return;
    int j = idx & 15;
    int lane = (idx >> 4) & 63;
    int step = (idx >> 10) % KSTEPS;
    int tile = idx / (KSTEPS << 10);
    int oc = tile * 32 + (lane & 31);
    int tap = step / CP;
    int cpair = step - tap * CP;
    int c = cpair * 32 + ((lane >> 5) << 4) + j;
    float v = w[((size_t)oc * I + c) * KK + tap];
    o[idx] = (signed char)(int)v;
}

// conv1 weights: OIHW [96][3][5][5] fp32 -> [96][128] int8, byte [oc][tap*4+c]
__global__ void cvt_w1(const float* __restrict__ w, signed char* __restrict__ o) {
    int idx = blockIdx.x * blockDim.x + threadIdx.x;
    if (idx >= 96 * 128) return;
    int b = idx & 127;
    int oc = idx >> 7;
    int tap = b >> 2;
    int c = b & 3;
    float v = (tap < 25 && c < 3) ? w[(oc * 3 + c) * 25 + tap] : 0.0f;
    o[idx] = (signed char)(int)v;
}

__global__ void cvt_i8(const float* __restrict__ w, signed char* __restrict__ o, int n) {
    int idx = blockIdx.x * blockDim.x + threadIdx.x;
    if (idx < n) o[idx] = (signed char)(int)w[idx];
}

__global__ void cvt_i32(const float* __restrict__ b, int* __restrict__ o, int n) {
    int idx = blockIdx.x * blockDim.x + threadIdx.x;
    if (idx < n) o[idx] = (int)b[idx];
}

// ---------------- quantize input: NCHW fp32 [512,3,32,32] -> NHWC int8 [512,32,32,4] ----------------

__global__ void quantize_in(const float* __restrict__ x, signed char* __restrict__ q, int total) {
    int idx = blockIdx.x * blockDim.x + threadIdx.x;
    if (idx >= total) return;
    int hw = idx & 1023;
    int n = idx >> 10;
    const float* xp = x + n * 3072 + hw;
    int b[4];
#pragma unroll
    for (int c = 0; c < 3; ++c) {
        float v = rintf(xp[c * 1024] / 0.05f);
        v = fminf(fmaxf(v, -128.0f), 127.0f);
        b[c] = (int)v;
    }
    b[3] = 0;
    int packed = (b[0] & 0xff) | ((b[1] & 0xff) << 8) | ((b[2] & 0xff) << 16) | (b[3] << 24);
    ((int*)q)[idx] = packed;
}

// ---------------- conv1 MFMA with LDS im2col (16x16x64, Cin=4) ----------------

__global__ void conv1_mfma(const signed char* __restrict__ act,
                           const signed char* __restrict__ wq,
                           const int* __restrict__ bias,
                           signed char* __restrict__ out) {
    __shared__ int lds[64 * 36];

    int tid = threadIdx.x;
    int lane = tid & 63;
    int wid = tid >> 6;
    int siteBase = blockIdx.x * 64;

    {
        int site_local = tid >> 2;
        int g = tid & 3;
        int site = siteBase + site_local;
        int ox = site & 31;
        int oy = (site >> 5) & 31;
        int n = site >> 10;
        const int* aI = (const int*)act;
        int* dst = lds + site_local * 36 + g * 8;
#pragma unroll
        for (int j = 0; j < 8; ++j) {
            int tap = g * 8 + j;
            int v = 0;
            if (tap < 25) {
                int ky = tap / 5;
                int kx = tap - ky * 5;
                int iy = oy - 2 + ky;
                int ix = ox - 2 + kx;
                if ((unsigned)iy < 32u && (unsigned)ix < 32u)
                    v = aI[(n << 10) + (iy << 5) + ix];
            }
            dst[j] = v;
        }
    }

    int m = lane & 15;
    int q = lane >> 4;

    i32x4 bfrag[6][2];
#pragma unroll
    for (int j = 0; j < 6; ++j)
#pragma unroll
        for (int s = 0; s < 2; ++s)
            bfrag[j][s] = *(const i32x4*)(wq + (j * 16 + m) * 128 + s * 64 + q * 16);

    i32x4 acc[6];
#pragma unroll
    for (int j = 0; j < 6; ++j) {
        int bv = bias[j * 16 + m];
        acc[j] = (i32x4){bv, bv, bv, bv};
    }

    __syncthreads();

#pragma unroll
    for (int s = 0; s < 2; ++s) {
        i32x4 a = *(const i32x4*)(lds + (wid * 16 + m) * 36 + s * 16 + q * 4);
#pragma unroll
        for (int j = 0; j < 6; ++j)
            acc[j] = __builtin_amdgcn_mfma_i32_16x16x64_i8(a, bfrag[j][s], acc[j], 0, 0, 0);
    }

#pragma unroll
    for (int j = 0; j < 6; ++j) {
        int oc = j * 16 + m;
#pragma unroll
        for (int r = 0; r < 4; ++r) {
            int site = siteBase + wid * 16 + q * 4 + r;
            float v = floorf((float)acc[j][r] * 2e-3f);
            v = fminf(fmaxf(v, 0.0f), 127.0f);
            out[(size_t)site * 96 + oc] = (signed char)v;
        }
    }
}

// ---------------- implicit-GEMM 32x32x32 MFMA conv/FC, padded act, LDS-staged B ----------------
// act: physically padded NHWC int8 (halo zeros), row stride PW (template), image stride
// imgStride (runtime). wqf: fragment-major [Cout/32][KSTEPS][64][16], K tap-major.
// Convs (KS>1, NG<=18): group loop fully unrolled -> constant tap/offsets.
// FC (KS==1): group loop ROLLED (full unroll of K=4096 is pathological: r5 41ms, r10 32ms);
// aoff = k16*32 needs one scalar mul per group only.
// grid.x = M/(128*SITES), grid.y = Cout/(OCT*32).

template <int KS, int CIN, int OCT, int SITES, int GSTEP, int OH, int OW, int PW>
__launch_bounds__(256, 2)
__global__ void conv_mfma32(const signed char* __restrict__ act,
                            const signed char* __restrict__ wqf,
                            const int* __restrict__ bias,
                            signed char* __restrict__ out,
                            int imgStride, int outImg, int outRow, int outOff,
                            int Cout, float M) {
    constexpr int CP = CIN / 32;
    constexpr int KSTEPS = KS * KS * CP;
    static_assert(KSTEPS % GSTEP == 0, "GSTEP must divide KSTEPS");
    constexpr int NG = KSTEPS / GSTEP;
    constexpr int UNITS = OCT * GSTEP;
    static_assert(UNITS % 4 == 0, "stage units split across 4 waves");
    constexpr int CHUNK = UNITS * 1024;

    __shared__ signed char lds[2 * CHUNK];

    int lane = threadIdx.x & 63;
    int wid = threadIdx.x >> 6;
    int m32 = lane & 31;
    int q2 = lane >> 5;
    int waveBase = blockIdx.x * (SITES * 128) + wid * (SITES * 32);
    int oc0 = blockIdx.y * (OCT * 32);

    const signed char* baseA[SITES];
#pragma unroll
    for (int s = 0; s < SITES; ++s) {
        int site = waveBase + s * 32 + m32;
        int ox = site % OW;
        int t = site / OW;
        int oy = t % OH;
        int n = t / OH;
        baseA[s] = act + ((size_t)n * imgStride + oy * PW + ox) * CIN + q2 * 16;
    }

    i32x16 acc[SITES][OCT];
#pragma unroll
    for (int j = 0; j < OCT; ++j) {
        int bv = bias[oc0 + j * 32 + m32];
#pragma unroll
        for (int s = 0; s < SITES; ++s)
#pragma unroll
            for (int r = 0; r < 16; ++r)
                acc[s][j][r] = bv;
    }

    const signed char* wblk = wqf + (size_t)(blockIdx.y * OCT) * KSTEPS * 1024;

    auto stage = [&](int buf, int g) {
#pragma unroll
        for (int t = 0; t < UNITS / 4; ++t) {
            int u = t * 4 + wid;                  // 1KB unit: u = j*GSTEP + s
            int j = u / GSTEP;
            int s = u - j * GSTEP;
            const signed char* gsrc =
                wblk + (((size_t)(j * KSTEPS + g * GSTEP + s)) << 10) + lane * 16;
            async_cp16(gsrc, lds + buf * CHUNK + (u << 10));
        }
    };

    auto body = [&](int g) {
        __syncthreads();
        if (g + 1 < NG) stage((g + 1) & 1, g + 1);

        const signed char* lb = lds + (g & 1) * CHUNK + lane * 16;
#pragma unroll
        for (int cp = 0; cp < GSTEP; ++cp) {
            int k16 = g * GSTEP + cp;
            int aoff;
            if constexpr (KS == 1) {
                aoff = k16 * 32;                  // one scalar mul per group (rolled)
            } else {
                int tap = k16 / CP;               // constant-folded (unrolled)
                int cpair = k16 - tap * CP;
                int ty = tap / KS;
                int tx = tap - ty * KS;
                aoff = (ty * PW + tx) * CIN + cpair * 32;
            }

            i32x4 a[SITES];
#pragma unroll
            for (int s = 0; s < SITES; ++s)
                a[s] = *(const i32x4*)(baseA[s] + aoff);    // unconditional: halo is zero
#pragma unroll
            for (int j = 0; j < OCT; ++j) {
                i32x4 b = *(const i32x4*)(lb + ((j * GSTEP + cp) << 10));
#pragma unroll
                for (int s = 0; s < SITES; ++s)
                    acc[s][j] = __builtin_amdgcn_mfma_i32_32x32x32_i8(a[s], b, acc[s][j], 0, 0, 0);
            }
        }
    };

    stage(0, 0);

    if constexpr (KS > 1) {
#pragma unroll
        for (int g = 0; g < NG; ++g) body(g);     // NG <= 18: constant-folds, I$-safe
    } else {
        for (int g = 0; g < NG; ++g) body(g);     // FC: rolled — never unroll K=4096
    }

    // D layout: col(oc) = lane&31, row(site) = (r&3) + 8*(r>>2) + 4*q2
#pragma unroll
    for (int s = 0; s < SITES; ++s) {
#pragma unroll
        for (int r = 0; r < 16; ++r) {
            int row = (r & 3) + 8 * (r >> 2) + 4 * q2;
            int site = waveBase + s * 32 + row;
            int ox = site % OW;
            int t = site / OW;
            int oy = t % OH;
            int n = t / OH;
            size_t base = (size_t)n * outImg + oy * outRow + ox * Cout + outOff + oc0 + m32;
#pragma unroll
            for (int j = 0; j < OCT; ++j) {
                float v = floorf((float)acc[s][j][r] * M);
                v = fminf(fmaxf(v, 0.0f), 127.0f);
                out[base + j * 32] = (signed char)v;
            }
        }
    }
}

// ---------------- maxpool 3x3 stride 2, NHWC, padded output (halo written as 0) ----------------

__global__ void qmaxpool(const signed char* __restrict__ in, signed char* __restrict__ out,
                         int N, int H, int W, int C4,
                         int OH, int OW, int OHp, int OWp, int opad, int total) {
    int idx = blockIdx.x * blockDim.x + threadIdx.x;
    if (idx >= total) return;
    int cc = idx % C4;
    int t = idx / C4;
    int oxp = t % OWp; t /= OWp;
    int oyp = t % OHp;
    int n = t / OHp;
    int oy = oyp - opad, ox = oxp - opad;
    int res = 0;
    if ((unsigned)oy < (unsigned)OH && (unsigned)ox < (unsigned)OW) {
        const int* ip = (const int*)in;
        int base = ((n * H + oy * 2) * W + ox * 2) * C4 + cc;
        int m0 = -128, m1 = -128, m2 = -128, m3 = -128;
#pragma unroll
        for (int dy = 0; dy < 3; ++dy)
#pragma unroll
            for (int dx = 0; dx < 3; ++dx) {
                int v = ip[base + (dy * W + dx) * C4];
                m0 = max(m0, (int)(signed char)(v & 0xff));
                m1 = max(m1, (int)(signed char)((v >> 8) & 0xff));
                m2 = max(m2, (int)(signed char)((v >> 16) & 0xff));
                m3 = max(m3, (int)(signed char)(v >> 24));
            }
        res = (m0 & 0xff) | ((m1 & 0xff) << 8) | ((m2 & 0xff) << 16) | (m3 << 24);
    }
    ((int*)out)[idx] = res;
}

// ---------------- global avg pool over 3x3 + floor: [512,3,3,256] -> [512,256] ----------------

__global__ void qgap(const signed char* __restrict__ in, signed char* __restrict__ out) {
    int idx = blockIdx.x * blockDim.x + threadIdx.x;
    if (idx >= 512 * 256) return;
    int c = idx & 255;
    int n = idx >> 8;
    const signed char* p = in + n * 9 * 256 + c;
    int s = 0;
#pragma unroll
    for (int k = 0; k < 9; ++k) s += p[k * 256];
    out[idx] = (signed char)(s / 9);
}

// ---------------- final FC (no relu), fp32 out: one wave per (b,o) ----------------

__global__ void qfc3_wave(const signed char* __restrict__ act,
                          const signed char* __restrict__ wq,
                          const int* __restrict__ bias,
                          float* __restrict__ out) {
    int gid = blockIdx.x * blockDim.x + threadIdx.x;
    int wave = gid >> 6;
    int lane = gid & 63;
    if (wave >= 512 * 10) return;
    int o = wave % 10;
    int b = wave / 10;
    const int* aI = (const int*)act + b * 1024;
    const int* wI = (const int*)wq + o * 1024;
    int acc = 0;
#pragma unroll
    for (int it = 0; it < 16; ++it) {
        int k = it * 64 + lane;
        acc = dot4(aI[k], wI[k], acc);
    }
#pragma unroll
    for (int s = 32; s; s >>= 1) acc += __shfl_xor(acc, s);
    if (lane == 0) {
        float v = floorf((float)(acc + bias[o]) * 2e-4f);
        v = fminf(fmaxf(v, -128.0f), 127.0f);
        out[b * 10 + o] = v;
    }
}

// ---------------- launch ----------------

#define LAUNCH(kern, n, ...) kern<<<dim3(((n) + 255) / 256), dim3(256), 0, stream>>>(__VA_ARGS__)

extern "C" void kernel_launch(void* const* d_in, const int* in_sizes, int n_in,
                              void* d_out, int out_size, void* d_ws, size_t ws_size,
                              hipStream_t stream) {
    const float* x   = (const float*)d_in[0];
    const float* w1  = (const float*)d_in[1];
    const float* b1  = (const float*)d_in[2];
    const float* w2  = (const float*)d_in[3];
    const float* b2  = (const float*)d_in[4];
    const float* w3  = (const float*)d_in[5];
    const float* b3  = (const float*)d_in[6];
    const float* w4  = (const float*)d_in[7];
    const float* b4  = (const float*)d_in[8];
    const float* w5  = (const float*)d_in[9];
    const float* b5  = (const float*)d_in[10];
    const float* wf1 = (const float*)d_in[11];
    const float* bf1 = (const float*)d_in[12];
    const float* wf2 = (const float*)d_in[13];
    const float* bf2 = (const float*)d_in[14];
    const float* wf3 = (const float*)d_in[15];
    const float* bf3 = (const float*)d_in[16];
    float* out = (float*)d_out;

    char* ws = (char*)d_ws;
    size_t off = 0;
    auto A = [&](size_t sz) -> size_t {
        size_t o = off;
        off += (sz + 255) & ~(size_t)255;
        return o;
    };

    size_t wq1  = A(96 * 128);
    size_t wq2  = A((size_t)8 * 75 * 1024);
    size_t wq3  = A((size_t)12 * 72 * 1024);
    size_t wq4  = A((size_t)12 * 108 * 1024);
    size_t wq5  = A((size_t)8 * 108 * 1024);
    size_t wqf1 = A((size_t)128 * 8 * 1024);
    size_t wqf2 = A((size_t)128 * 128 * 1024);
    size_t wqf3 = A(10 * 4096);
    size_t bq1  = A(96 * 4);
    size_t bq2  = A(256 * 4);
    size_t bq3  = A(384 * 4);
    size_t bq4  = A(384 * 4);
    size_t bq5  = A(256 * 4);
    size_t bqf1 = A(4096 * 4);
    size_t bqf2 = A(4096 * 4);
    size_t bqf3 = A(10 * 4);
    size_t bufQ = A(2097152);                  // quantized input [512,32,32,4]
    size_t bufR1 = A(50331648);                // C1 -> C2 -> {C5, P3, G, F1, F2, C4}
    size_t bufR2 = A(17743872);                // P1 [512,19,19,96] -> C3 [512,9,9,384]
    size_t bufR3 = A(10616832);                // P2 [512,9,9,256]
    if (off > ws_size) return;

    signed char* W1 = (signed char*)(ws + wq1);
    signed char* W2 = (signed char*)(ws + wq2);
    signed char* W3 = (signed char*)(ws + wq3);
    signed char* W4 = (signed char*)(ws + wq4);
    signed char* W5 = (signed char*)(ws + wq5);
    signed char* WF1 = (signed char*)(ws + wqf1);
    signed char* WF2 = (signed char*)(ws + wqf2);
    signed char* WF3 = (signed char*)(ws + wqf3);
    int* B1 = (int*)(ws + bq1);
    int* B2 = (int*)(ws + bq2);
    int* B3 = (int*)(ws + bq3);
    int* B4 = (int*)(ws + bq4);
    int* B5 = (int*)(ws + bq5);
    int* BF1 = (int*)(ws + bqf1);
    int* BF2 = (int*)(ws + bqf2);
    int* BF3 = (int*)(ws + bqf3);

    signed char* Q  = (signed char*)(ws + bufQ);
    signed char* C1 = (signed char*)(ws + bufR1);             // [512,32,32,96]
    signed char* C2 = (signed char*)(ws + bufR1);             // [512,15,15,256] (C1 dead)
    signed char* C5 = (signed char*)(ws + bufR1);             // [512,7,7,256]  (C2 dead)
    signed char* P3 = (signed char*)(ws + bufR1 + 7340032);   // [512,3,3,256]
    signed char* G  = (signed char*)(ws + bufR1 + 9437184);   // [512,256]
    signed char* F1 = (signed char*)(ws + bufR1 + 10485760);  // [512,4096]
    signed char* F2 = (signed char*)(ws + bufR1 + 13631488);  // [512,4096]
    signed char* C4 = (signed char*)(ws + bufR1 + 31457280);  // [512,9,9,384] padded
    signed char* P1 = (signed char*)(ws + bufR2);             // [512,19,19,96] padded
    signed char* C3 = (signed char*)(ws + bufR2);             // [512,9,9,384] padded (P1 dead)
    signed char* P2 = (signed char*)(ws + bufR3);             // [512,9,9,256] padded

    // ---- weight/bias conversion ----
    LAUNCH(cvt_w1, 96 * 128, w1, W1);
    LAUNCH(cvt_w_frag32, 8 * 75 * 1024, w2, W2, 256, 96, 25, 3, 75);
    LAUNCH(cvt_w_frag32, 12 * 72 * 1024, w3, W3, 384, 256, 9, 8, 72);
    LAUNCH(cvt_w_frag32, 12 * 108 * 1024, w4, W4, 384, 384, 9, 12, 108);
    LAUNCH(cvt_w_frag32, 8 * 108 * 1024, w5, W5, 256, 384, 9, 12, 108);
    LAUNCH(cvt_w_frag32, 128 * 8 * 1024, wf1, WF1, 4096, 256, 1, 8, 8);
    LAUNCH(cvt_w_frag32, 128 * 128 * 1024, wf2, WF2, 4096, 4096, 1, 128, 128);
    LAUNCH(cvt_i8, 10 * 4096, wf3, WF3, 10 * 4096);
    LAUNCH(cvt_i32, 96, b1, B1, 96);
    LAUNCH(cvt_i32, 256, b2, B2, 256);
    LAUNCH(cvt_i32, 384, b3, B3, 384);
    LAUNCH(cvt_i32, 384, b4, B4, 384);
    LAUNCH(cvt_i32, 256, b5, B5, 256);
    LAUNCH(cvt_i32, 4096, bf1, BF1, 4096);
    LAUNCH(cvt_i32, 4096, bf2, BF2, 4096);
    LAUNCH(cvt_i32, 10, bf3, BF3, 10);

    // ---- forward ----
    LAUNCH(quantize_in, 512 * 1024, x, Q, 512 * 1024);

    // conv1: Q -> C1 [512,32,32,96]
    conv1_mfma<<<dim3(512 * 1024 / 64), dim3(256), 0, stream>>>(Q, W1, B1, C1);

    // pool1: C1 -> P1 padded [512,19,19,96] (halo zeros)
    LAUNCH(qmaxpool, 512 * 19 * 19 * 24, C1, P1, 512, 32, 32, 24, 15, 15, 19, 19, 2,
           512 * 19 * 19 * 24);

    // conv2: P1 -> C2 [512,15,15,256]; GSTEP=5, NG=15, LDS 40 KB
    conv_mfma32<5, 96, 4, 2, 5, 15, 15, 19><<<dim3(450, 2), dim3(256), 0, stream>>>(
        P1, W2, B2, C2, 361, 225 * 256, 15 * 256, 0, 256, 4e-4f);

    // pool2: C2 -> P2 padded [512,9,9,256]
    LAUNCH(qmaxpool, 512 * 9 * 9 * 64, C2, P2, 512, 15, 15, 64, 7, 7, 9, 9, 1,
           512 * 9 * 9 * 64);

    // zero halos of conv3/conv4 padded outputs
    hipMemsetAsync(C3, 0, 512 * 9 * 9 * 384, stream);
    hipMemsetAsync(C4, 0, 512 * 9 * 9 * 384, stream);

    // conv3: P2 -> C3 padded [512,9,9,384]; GSTEP=6, NG=12, LDS 48 KB
    conv_mfma32<3, 256, 4, 2, 6, 7, 7, 9><<<dim3(98, 3), dim3(256), 0, stream>>>(
        P2, W3, B3, C3, 81, 81 * 384, 9 * 384, 10 * 384, 384, 2e-4f);

    // conv4: C3 -> C4 padded [512,9,9,384]; GSTEP=6, NG=18
    conv_mfma32<3, 384, 4, 2, 6, 7, 7, 9><<<dim3(98, 3), dim3(256), 0, stream>>>(
        C3, W4, B4, C4, 81, 81 * 384, 9 * 384, 10 * 384, 384, 2e-4f);

    // conv5: C4 -> C5 [512,7,7,256]; GSTEP=6, NG=18
    conv_mfma32<3, 384, 4, 2, 6, 7, 7, 9><<<dim3(98, 2), dim3(256), 0, stream>>>(
        C4, W5, B5, C5, 81, 49 * 256, 7 * 256, 0, 256, 2e-4f);

    // pool3: C5 -> P3 [512,3,3,256] (unpadded)
    LAUNCH(qmaxpool, 512 * 3 * 3 * 64, C5, P3, 512, 7, 7, 64, 3, 3, 3, 3, 0,
           512 * 3 * 3 * 64);

    // gap: P3 -> G [512,256]
    LAUNCH(qgap, 512 * 256, P3, G);

    // fc1: G -> F1 [512,4096]; rolled K-loop, NG=1, LDS 32 KB
    conv_mfma32<1, 256, 2, 2, 8, 1, 1, 1><<<dim3(2, 64), dim3(256), 0, stream>>>(
        G, WF1, BF1, F1, 1, 4096, 4096, 0, 4096, 1e-3f);

    // fc2: F1 -> F2 [512,4096]; rolled K-loop, NG=16, LDS 32 KB (NEVER fully unroll K=4096)
    conv_mfma32<1, 4096, 2, 2, 8, 1, 1, 1><<<dim3(2, 64), dim3(256), 0, stream>>>(
        F1, WF2, BF2, F2, 1, 4096, 4096, 0, 4096, 2e-4f);

    // fc3: F2 -> out [512,10] fp32
    qfc3_wave<<<dim3(512 * 10 * 64 / 256), dim3(256), 0, stream>>>(F2, WF3, BF3, out);
}